// Round 14
// baseline (1190.652 us; speedup 1.0000x reference)
//
#include <hip/hip_runtime.h>

#define T_TOK 4096
#define H_DIM 2048
#define I_DIM 5632
#define NE 8

typedef _Float16 f16;
typedef _Float16 f16x8 __attribute__((ext_vector_type(8)));
typedef float f32x4 __attribute__((ext_vector_type(4)));

// ---- workspace layout (byte offsets) ----
#define OFF_META   0                         // counts[8] | offs[8] | cursor[8]
#define OFF_BTOK   256
#define OFF_BW     (256 + 32768)
#define OFF_RE     (256 + 2 * 32768)
#define OFF_RW     (256 + 3 * 32768)
#define OFF_TP     (256 + 4 * 32768)
#define OFF_HSB    (256 + 5 * 32768)
#define OFF_WF     (OFF_HSB + (size_t)T_TOK * H_DIM * 2)   // f16 weight area starts here

typedef const __attribute__((address_space(1))) unsigned int guint;
typedef __attribute__((address_space(3))) unsigned int luint;

// 8-slot (16B) XOR swizzle within a 128-byte LDS row: conflict-free reads (verified R3-R13)
__device__ __forceinline__ int swzk(int r, int bir) {
    return (bir & 15) | ((((bir >> 4) ^ r) & 7) << 4);
}

// ---------------- f32 -> f16 streaming convert (fallback path) ----------------
__global__ void cvt_w_kernel(const float* __restrict__ src, f16* __restrict__ dst, int n8) {
    int stride = gridDim.x * blockDim.x;
    for (int i = blockIdx.x * blockDim.x + threadIdx.x; i < n8; i += stride) {
        size_t b = (size_t)i * 8;
        float4 a = *(const float4*)(src + b);
        float4 c = *(const float4*)(src + b + 4);
        f16x8 v;
        v[0] = (f16)a.x; v[1] = (f16)a.y; v[2] = (f16)a.z; v[3] = (f16)a.w;
        v[4] = (f16)c.x; v[5] = (f16)c.y; v[6] = (f16)c.z; v[7] = (f16)c.w;
        *(f16x8*)(dst + b) = v;
    }
}

// ---------------- fused prep: w13 cvt | hs cvt | gate (independent block roles) ----------------
__global__ void prep_kernel(const float* __restrict__ w13, f16* __restrict__ w13f, int n8_w13,
                            int cvt13_b,
                            const float* __restrict__ hs, f16* __restrict__ hsb,
                            const float* __restrict__ gw,
                            int* __restrict__ re, float* __restrict__ rw,
                            int* __restrict__ counts) {
    int id = blockIdx.x;
    if (id < cvt13_b) {
        int stride = cvt13_b * 256;
        for (int i = id * 256 + threadIdx.x; i < n8_w13; i += stride) {
            size_t b = (size_t)i * 8;
            float4 a = *(const float4*)(w13 + b);
            float4 c = *(const float4*)(w13 + b + 4);
            f16x8 v;
            v[0] = (f16)a.x; v[1] = (f16)a.y; v[2] = (f16)a.z; v[3] = (f16)a.w;
            v[4] = (f16)c.x; v[5] = (f16)c.y; v[6] = (f16)c.z; v[7] = (f16)c.w;
            *(f16x8*)(w13f + b) = v;
        }
        return;
    }
    id -= cvt13_b;
    if (id < 1024) {
        const int n8 = T_TOK * H_DIM / 8;
        int stride = 1024 * 256;
        for (int i = id * 256 + threadIdx.x; i < n8; i += stride) {
            size_t b = (size_t)i * 8;
            float4 a = *(const float4*)(hs + b);
            float4 c = *(const float4*)(hs + b + 4);
            f16x8 v;
            v[0] = (f16)a.x; v[1] = (f16)a.y; v[2] = (f16)a.z; v[3] = (f16)a.w;
            v[4] = (f16)c.x; v[5] = (f16)c.y; v[6] = (f16)c.z; v[7] = (f16)c.w;
            *(f16x8*)(hsb + b) = v;
        }
        return;
    }
    id -= 1024;   // gate: 1024 blocks x 4 tokens
    int lane = threadIdx.x & 63;
    int t = id * 4 + (threadIdx.x >> 6);
    float acc[NE];
#pragma unroll
    for (int e = 0; e < NE; ++e) acc[e] = 0.f;
    const float* x = hs + (size_t)t * H_DIM;
    for (int i = lane; i < H_DIM; i += 64) {
        float xv = x[i];
#pragma unroll
        for (int e = 0; e < NE; ++e) acc[e] += xv * gw[e * H_DIM + i];
    }
#pragma unroll
    for (int e = 0; e < NE; ++e)
        for (int off = 32; off > 0; off >>= 1) acc[e] += __shfl_xor(acc[e], off);
    if (lane == 0) {
        int i1 = 0; float l1 = acc[0];
#pragma unroll
        for (int e = 1; e < NE; ++e) if (acc[e] > l1) { l1 = acc[e]; i1 = e; }
        int i2 = -1; float l2 = -1e30f;
#pragma unroll
        for (int e = 0; e < NE; ++e) if (e != i1 && acc[e] > l2) { l2 = acc[e]; i2 = e; }
        float aa = __expf(l2 - l1);
        float s = 1.f / (1.f + aa);
        re[t * 2] = i1; re[t * 2 + 1] = i2;
        rw[t * 2] = s;  rw[t * 2 + 1] = aa * s;
        atomicAdd(&counts[i1], 1);
        atomicAdd(&counts[i2], 1);
    }
}

__global__ void scan_kernel(int* __restrict__ meta) {
    if (threadIdx.x == 0) {
        int s = 0;
        for (int e = 0; e < NE; ++e) { meta[8 + e] = s; meta[16 + e] = s; s += meta[e]; }
    }
}

__global__ void place_kernel(const int* __restrict__ re, const float* __restrict__ rw,
                             int* __restrict__ cursor, int* __restrict__ btok,
                             float* __restrict__ bwv, int* __restrict__ tpos) {
    int t = blockIdx.x * 256 + threadIdx.x;
    if (t >= T_TOK) return;
#pragma unroll
    for (int s = 0; s < 2; ++s) {
        int e = re[t * 2 + s];
        int p = atomicAdd(&cursor[e], 1);
        btok[p] = t;
        bwv[p] = rw[t * 2 + s];
        tpos[t * 2 + s] = p;
    }
}

// Panel-pinned XCD decode (validated R3-R13): panel P = sg*8 + (id&7) lives entirely
// on XCD id%8 (its 32 by-blocks are ids sg*256 + by*8 + x, all congruent mod 8).
__device__ __forceinline__ void decode_panel(int id, int npx, int e_arg,
                                             int& e, int& bx, int& by) {
    if (e_arg >= 0) { e = e_arg; bx = id >> 5; by = id & 31; return; }
    int sg  = id >> 8;
    int rem = id & 255;
    by = rem >> 3;
    int P = sg * 8 + (rem & 7);
    e = P / npx; bx = P % npx;
}

// ---------------- GEMM1 (+fused w2 convert): h = silu(X@Wg^T) * (X@Wu^T) ----------------
// m97-style single-buffer 2-barrier loop, all operands via global_load_lds (f16).
// BN widened to 128 h-cols (256 weight rows): halves hsb L3 re-read panels 88->44.
// BM=128, BK=64, 512 thr / 8 waves (2m x 4n), wave = 64 rows x (32 g + 32 u), rho=0.5.
// LDS 48 KB -> >=2 blocks/CU (16 waves). Blocks id < cvt_blocks stream-convert w2.
__global__ __launch_bounds__(512, 4) void gemm1_kernel(
    const f16* __restrict__ w13f, const f16* __restrict__ hsb, f16* __restrict__ hb,
    const int* __restrict__ counts, const int* __restrict__ offs,
    const int* __restrict__ btok,
    const float* __restrict__ cvt_src, f16* __restrict__ cvt_dst, int cvt_n8, int cvt_blocks,
    int e_arg, int global_h)
{
    if ((int)blockIdx.x < cvt_blocks) {
        int stride = cvt_blocks * 512;
        for (int i = blockIdx.x * 512 + threadIdx.x; i < cvt_n8; i += stride) {
            size_t b = (size_t)i * 8;
            float4 a = *(const float4*)(cvt_src + b);
            float4 c = *(const float4*)(cvt_src + b + 4);
            f16x8 v;
            v[0] = (f16)a.x; v[1] = (f16)a.y; v[2] = (f16)a.z; v[3] = (f16)a.w;
            v[4] = (f16)c.x; v[5] = (f16)c.y; v[6] = (f16)c.z; v[7] = (f16)c.w;
            *(f16x8*)(cvt_dst + b) = v;
        }
        return;
    }
    int e, bx, by;
    decode_panel((int)blockIdx.x - cvt_blocks, 44, e_arg, e, bx, by);
    const int n_e = counts[e];
    if (by * 128 >= n_e) return;
    const int boff = offs[e];
    const f16* We = (e_arg >= 0) ? w13f : (w13f + (size_t)e * (2 * I_DIM) * H_DIM);

    const int tid = threadIdx.x;
    const int lane = tid & 63;
    const int wid = tid >> 6;          // 0..7
    const int wm = wid >> 2;           // 0..1
    const int wn = wid & 3;            // 0..3
    const int l15 = lane & 15;

    __shared__ f16 As[128 * 64];   // 16 KB
    __shared__ f16 Bs[256 * 64];   // 32 KB (rows 0-127 g, 128-255 u)

    // DMA: A chunk c = i*512+tid -> LDS row c>>3, slot c&7 (dest linear c*16);
    // global k-slot = (c&7)^(r&7): inverse of the read swizzle (verified R5+).
    const f16* gA[2]; int dA[2];
#pragma unroll
    for (int i = 0; i < 2; ++i) {
        int c = i * 512 + tid;
        int r = c >> 3;                // 0..127
        dA[i] = c * 16;
        int slot = ((c & 7) ^ (r & 7)) * 8;
        int idx = by * 128 + r;
        idx = idx < n_e ? idx : n_e - 1;
        gA[i] = hsb + (size_t)btok[boff + idx] * H_DIM + slot;
    }
    const f16* gB[4]; int dB[4];
#pragma unroll
    for (int j = 0; j < 4; ++j) {
        int c = j * 512 + tid;
        int r = c >> 3;                // 0..255
        dB[j] = c * 16;
        int slot = ((c & 7) ^ (r & 7)) * 8;
        int wrow = (r < 128) ? (bx * 128 + r) : (I_DIM + bx * 128 + (r - 128));
        gB[j] = We + (size_t)wrow * H_DIM + slot;
    }

    f32x4 ag[4][2], au[4][2];
#pragma unroll
    for (int m = 0; m < 4; ++m)
#pragma unroll
        for (int n = 0; n < 2; ++n) { ag[m][n] = (f32x4)0.f; au[m][n] = (f32x4)0.f; }

    const int NT = H_DIM / 64;   // 32

#pragma unroll 1
    for (int kt = 0; kt < NT; ++kt) {
        __syncthreads();
        const int k0 = kt * 64;
#pragma unroll
        for (int i = 0; i < 2; ++i)
            __builtin_amdgcn_global_load_lds((guint*)(gA[i] + k0), (luint*)((char*)As + dA[i]), 16, 0, 0);
#pragma unroll
        for (int j = 0; j < 4; ++j)
            __builtin_amdgcn_global_load_lds((guint*)(gB[j] + k0), (luint*)((char*)Bs + dB[j]), 16, 0, 0);
        __syncthreads();          // implicit vmcnt(0): tile kt landed
#pragma unroll
        for (int kh = 0; kh < 2; ++kh) {
            const int kb = kh * 64 + (lane >> 4) * 16;
            f16x8 a[4], bg[2], bu[2];
#pragma unroll
            for (int m = 0; m < 4; ++m) {
                int r = wm * 64 + m * 16 + l15;
                a[m] = *(const f16x8*)((const char*)As + r * 128 + swzk(r, kb));
            }
#pragma unroll
            for (int n = 0; n < 2; ++n) {
                int rg = wn * 32 + n * 16 + l15;
                bg[n] = *(const f16x8*)((const char*)Bs + rg * 128 + swzk(rg, kb));
                int ru = 128 + rg;
                bu[n] = *(const f16x8*)((const char*)Bs + ru * 128 + swzk(ru, kb));
            }
#pragma unroll
            for (int m = 0; m < 4; ++m)
#pragma unroll
                for (int n = 0; n < 2; ++n) {
                    ag[m][n] = __builtin_amdgcn_mfma_f32_16x16x32_f16(a[m], bg[n], ag[m][n], 0, 0, 0);
                    au[m][n] = __builtin_amdgcn_mfma_f32_16x16x32_f16(a[m], bu[n], au[m][n], 0, 0, 0);
                }
        }
    }

    // epilogue: silu(g)*u -> f16 h
    const int hbase = (global_h ? boff : 0) + by * 128;
#pragma unroll
    for (int m = 0; m < 4; ++m) {
        int rl0 = wm * 64 + m * 16 + ((lane >> 4) << 2);
#pragma unroll
        for (int r = 0; r < 4; ++r) {
            int rl = rl0 + r;
            if (by * 128 + rl < n_e) {
#pragma unroll
                for (int n = 0; n < 2; ++n) {
                    float g = ag[m][n][r];
                    float u = au[m][n][r];
                    float h = g / (1.f + __expf(-g)) * u;
                    hb[(size_t)(hbase + rl) * I_DIM + bx * 128 + wn * 32 + n * 16 + l15] = (f16)h;
                }
            }
        }
    }
}

// ---------------- GEMM2: y[p] = h[p] @ w2^T  (atomic-free, BN=256) ----------------
// Same single-buffer 2-barrier loop; BM=128 x BN=256, BK=64, 512 thr / 8 waves
// (2m x 4n), wave 64x64. LDS 48 KB; halves h re-read traffic vs BN=128.
__global__ __launch_bounds__(512, 4) void gemm2_kernel(
    const f16* __restrict__ w2f, const f16* __restrict__ hb, float* __restrict__ y,
    const int* __restrict__ counts, const int* __restrict__ offs,
    const int* __restrict__ btok, int e_arg, int global_h)
{
    int e, bx, by;
    decode_panel(blockIdx.x, 8, e_arg, e, bx, by);
    const int n_e = counts[e];
    if (by * 128 >= n_e) return;
    const int boff = offs[e];
    const f16* We = (e_arg >= 0) ? w2f : (w2f + (size_t)e * H_DIM * I_DIM);

    const int tid = threadIdx.x;
    const int lane = tid & 63;
    const int wid = tid >> 6;          // 0..7
    const int wm = wid >> 2;           // 0..1
    const int wn = wid & 3;            // 0..3
    const int l15 = lane & 15;

    __shared__ f16 As[128 * 64];       // 16 KB
    __shared__ f16 Bs[256 * 64];       // 32 KB

    const int hb0 = global_h ? boff : 0;
    const f16* gA[2]; int dA[2];
#pragma unroll
    for (int i = 0; i < 2; ++i) {
        int c = i * 512 + tid;
        int r = c >> 3;                // 0..127
        dA[i] = c * 16;
        int slot = ((c & 7) ^ (r & 7)) * 8;
        int idx = by * 128 + r;
        idx = idx < n_e ? idx : n_e - 1;
        gA[i] = hb + (size_t)(hb0 + idx) * I_DIM + slot;
    }
    const f16* gB[4]; int dB[4];
#pragma unroll
    for (int j = 0; j < 4; ++j) {
        int c = j * 512 + tid;
        int r = c >> 3;                // 0..255
        dB[j] = c * 16;
        int slot = ((c & 7) ^ (r & 7)) * 8;
        gB[j] = We + (size_t)(bx * 256 + r) * I_DIM + slot;
    }

    f32x4 acc[4][4];
#pragma unroll
    for (int m = 0; m < 4; ++m)
#pragma unroll
        for (int n = 0; n < 4; ++n) acc[m][n] = (f32x4)0.f;

    const int NT = I_DIM / 64;   // 88

#pragma unroll 1
    for (int kt = 0; kt < NT; ++kt) {
        __syncthreads();
        const int k0 = kt * 64;
#pragma unroll
        for (int i = 0; i < 2; ++i)
            __builtin_amdgcn_global_load_lds((guint*)(gA[i] + k0), (luint*)((char*)As + dA[i]), 16, 0, 0);
#pragma unroll
        for (int j = 0; j < 4; ++j)
            __builtin_amdgcn_global_load_lds((guint*)(gB[j] + k0), (luint*)((char*)Bs + dB[j]), 16, 0, 0);
        __syncthreads();
#pragma unroll
        for (int kh = 0; kh < 2; ++kh) {
            const int kb = kh * 64 + (lane >> 4) * 16;
            f16x8 a[4], b[4];
#pragma unroll
            for (int m = 0; m < 4; ++m) {
                int r = wm * 64 + m * 16 + l15;
                a[m] = *(const f16x8*)((const char*)As + r * 128 + swzk(r, kb));
            }
#pragma unroll
            for (int n = 0; n < 4; ++n) {
                int r = wn * 64 + n * 16 + l15;
                b[n] = *(const f16x8*)((const char*)Bs + r * 128 + swzk(r, kb));
            }
#pragma unroll
            for (int m = 0; m < 4; ++m)
#pragma unroll
                for (int n = 0; n < 4; ++n)
                    acc[m][n] = __builtin_amdgcn_mfma_f32_16x16x32_f16(a[m], b[n], acc[m][n], 0, 0, 0);
        }
    }

    // epilogue: plain stores into y (each bucket row owned by exactly one block)
#pragma unroll
    for (int m = 0; m < 4; ++m) {
        int rl0 = wm * 64 + m * 16 + ((lane >> 4) << 2);
#pragma unroll
        for (int r = 0; r < 4; ++r) {
            int rl = rl0 + r;
            if (by * 128 + rl < n_e) {
                int p = boff + by * 128 + rl;
#pragma unroll
                for (int n = 0; n < 4; ++n)
                    y[(size_t)p * H_DIM + bx * 256 + wn * 64 + n * 16 + l15] = acc[m][n][r];
            }
        }
    }
}

// ---------------- reduce: out[t] = w0*y[p0] + w1*y[p1] ----------------
__global__ void reduce_kernel(const float* __restrict__ y, const int* __restrict__ tpos,
                              const float* __restrict__ bwv, float* __restrict__ out) {
    int t = blockIdx.x;
    int p0 = tpos[t * 2], p1 = tpos[t * 2 + 1];
    float w0 = bwv[p0], w1 = bwv[p1];
    const float4* y0 = (const float4*)(y + (size_t)p0 * H_DIM);
    const float4* y1 = (const float4*)(y + (size_t)p1 * H_DIM);
    float4* o = (float4*)(out + (size_t)t * H_DIM);
    for (int i = threadIdx.x; i < H_DIM / 4; i += 256) {
        float4 a = y0[i], b = y1[i];
        float4 r;
        r.x = w0 * a.x + w1 * b.x;
        r.y = w0 * a.y + w1 * b.y;
        r.z = w0 * a.z + w1 * b.z;
        r.w = w0 * a.w + w1 * b.w;
        o[i] = r;
    }
}

extern "C" void kernel_launch(void* const* d_in, const int* in_sizes, int n_in,
                              void* d_out, int out_size, void* d_ws, size_t ws_size,
                              hipStream_t stream) {
    const float* hs  = (const float*)d_in[0];
    const float* gw  = (const float*)d_in[1];
    const float* w13 = (const float*)d_in[2];
    const float* w2  = (const float*)d_in[3];
    float* out = (float*)d_out;

    char* ws = (char*)d_ws;
    int*   meta = (int*)(ws + OFF_META);
    int*   btok = (int*)(ws + OFF_BTOK);
    float* bwv  = (float*)(ws + OFF_BW);
    int*   re   = (int*)(ws + OFF_RE);
    float* rw   = (float*)(ws + OFF_RW);
    int*   tpos = (int*)(ws + OFF_TP);
    f16*   hsb  = (f16*)(ws + OFF_HSB);

    hipMemsetAsync(meta, 0, 256, stream);

    const size_t w13_elems = (size_t)NE * 2 * I_DIM * H_DIM;   // 184,549,376
    const size_t w2_elems  = (size_t)NE * H_DIM * I_DIM;       //  92,274,688

    // full-f16 path layout
    size_t o_w13f = OFF_WF;
    size_t o_w2f  = o_w13f + w13_elems * 2;
    size_t o_hb   = o_w2f + w2_elems * 2;
    size_t o_y    = o_hb + (size_t)2 * T_TOK * I_DIM * 2;
    size_t need_full = o_y + (size_t)2 * T_TOK * H_DIM * 4;

    // per-expert fallback layout
    size_t f_w13 = OFF_WF;
    size_t f_w2  = f_w13 + (size_t)2 * I_DIM * H_DIM * 2;
    size_t f_hb  = f_w2 + (size_t)H_DIM * I_DIM * 2;
    size_t f_y   = f_hb + (size_t)T_TOK * I_DIM * 2;

    if (ws_size >= need_full) {
        f16* w13f = (f16*)(ws + o_w13f);
        f16* w2f  = (f16*)(ws + o_w2f);
        f16* hb   = (f16*)(ws + o_hb);
        float* y  = (float*)(ws + o_y);
        // fused prep: 3072 w13-cvt + 1024 hs-cvt + 1024 gate blocks
        prep_kernel<<<3072 + 1024 + 1024, 256, 0, stream>>>(
            w13, w13f, (int)(w13_elems / 8), 3072, hs, hsb, gw, re, rw, meta);
        scan_kernel<<<1, 64, 0, stream>>>(meta);
        place_kernel<<<T_TOK / 256, 256, 0, stream>>>(re, rw, meta + 16, btok, bwv, tpos);
        // gemm1: 1024 fused w2-convert blocks + 352 panels x 32 by (BN=128 h-cols)
        gemm1_kernel<<<1024 + 352 * 32, 512, 0, stream>>>(
            w13f, hsb, hb, meta, meta + 8, btok,
            w2, w2f, (int)(w2_elems / 8), 1024, -1, 1);
        gemm2_kernel<<<64 * 32, 512, 0, stream>>>(w2f, hb, y, meta, meta + 8, btok, -1, 1);
        reduce_kernel<<<T_TOK, 256, 0, stream>>>(y, tpos, bwv, out);
    } else {
        f16* w13f = (f16*)(ws + f_w13);
        f16* w2f  = (f16*)(ws + f_w2);
        f16* hb   = (f16*)(ws + f_hb);
        float* y  = (float*)(ws + f_y);
        prep_kernel<<<1024 + 1024, 256, 0, stream>>>(
            w13, (f16*)nullptr, 0, 0, hs, hsb, gw, re, rw, meta);
        scan_kernel<<<1, 64, 0, stream>>>(meta);
        place_kernel<<<T_TOK / 256, 256, 0, stream>>>(re, rw, meta + 16, btok, bwv, tpos);
        const size_t w13_slice = (size_t)2 * I_DIM * H_DIM;
        const size_t w2_slice  = (size_t)H_DIM * I_DIM;
        for (int e = 0; e < NE; ++e) {
            cvt_w_kernel<<<2048, 256, 0, stream>>>(w13 + e * w13_slice, w13f, (int)(w13_slice / 8));
            gemm1_kernel<<<1024 + 44 * 32, 512, 0, stream>>>(
                w13f, hsb, hb, meta, meta + 8, btok,
                w2 + e * w2_slice, w2f, (int)(w2_slice / 8), 1024, e, 0);
            gemm2_kernel<<<8 * 32, 512, 0, stream>>>(w2f, hb, y, meta, meta + 8, btok, e, 0);
        }
        reduce_kernel<<<T_TOK, 256, 0, stream>>>(y, tpos, bwv, out);
    }
}

// Round 15
// 1126.483 us; speedup vs baseline: 1.0570x; 1.0570x over previous
//
#include <hip/hip_runtime.h>

#define T_TOK 4096
#define H_DIM 2048
#define I_DIM 5632
#define NE 8

typedef _Float16 f16;
typedef _Float16 f16x8 __attribute__((ext_vector_type(8)));
typedef float f32x4 __attribute__((ext_vector_type(4)));

// ---- workspace layout (byte offsets) ----
#define OFF_META   0                         // counts[8] | offs[8] | cursor[8]
#define OFF_BTOK   256
#define OFF_BW     (256 + 32768)
#define OFF_RE     (256 + 2 * 32768)
#define OFF_RW     (256 + 3 * 32768)
#define OFF_TP     (256 + 4 * 32768)
#define OFF_HSB    (256 + 5 * 32768)
#define OFF_WF     (OFF_HSB + (size_t)T_TOK * H_DIM * 2)   // f16 weight area starts here

typedef const __attribute__((address_space(1))) unsigned int guint;
typedef __attribute__((address_space(3))) unsigned int luint;

// 8-slot (16B) XOR swizzle within a 128-byte LDS row: conflict-free reads (verified R3-R14)
__device__ __forceinline__ int swzk(int r, int bir) {
    return (bir & 15) | ((((bir >> 4) ^ r) & 7) << 4);
}

// ---------------- f32 -> f16 streaming convert (fallback path) ----------------
__global__ void cvt_w_kernel(const float* __restrict__ src, f16* __restrict__ dst, int n8) {
    int stride = gridDim.x * blockDim.x;
    for (int i = blockIdx.x * blockDim.x + threadIdx.x; i < n8; i += stride) {
        size_t b = (size_t)i * 8;
        float4 a = *(const float4*)(src + b);
        float4 c = *(const float4*)(src + b + 4);
        f16x8 v;
        v[0] = (f16)a.x; v[1] = (f16)a.y; v[2] = (f16)a.z; v[3] = (f16)a.w;
        v[4] = (f16)c.x; v[5] = (f16)c.y; v[6] = (f16)c.z; v[7] = (f16)c.w;
        *(f16x8*)(dst + b) = v;
    }
}

// ---------------- fused prep: w13 cvt | hs cvt | gate (independent block roles) ----------------
__global__ void prep_kernel(const float* __restrict__ w13, f16* __restrict__ w13f, int n8_w13,
                            int cvt13_b,
                            const float* __restrict__ hs, f16* __restrict__ hsb,
                            const float* __restrict__ gw,
                            int* __restrict__ re, float* __restrict__ rw,
                            int* __restrict__ counts) {
    int id = blockIdx.x;
    if (id < cvt13_b) {
        int stride = cvt13_b * 256;
        for (int i = id * 256 + threadIdx.x; i < n8_w13; i += stride) {
            size_t b = (size_t)i * 8;
            float4 a = *(const float4*)(w13 + b);
            float4 c = *(const float4*)(w13 + b + 4);
            f16x8 v;
            v[0] = (f16)a.x; v[1] = (f16)a.y; v[2] = (f16)a.z; v[3] = (f16)a.w;
            v[4] = (f16)c.x; v[5] = (f16)c.y; v[6] = (f16)c.z; v[7] = (f16)c.w;
            *(f16x8*)(w13f + b) = v;
        }
        return;
    }
    id -= cvt13_b;
    if (id < 1024) {
        const int n8 = T_TOK * H_DIM / 8;
        int stride = 1024 * 256;
        for (int i = id * 256 + threadIdx.x; i < n8; i += stride) {
            size_t b = (size_t)i * 8;
            float4 a = *(const float4*)(hs + b);
            float4 c = *(const float4*)(hs + b + 4);
            f16x8 v;
            v[0] = (f16)a.x; v[1] = (f16)a.y; v[2] = (f16)a.z; v[3] = (f16)a.w;
            v[4] = (f16)c.x; v[5] = (f16)c.y; v[6] = (f16)c.z; v[7] = (f16)c.w;
            *(f16x8*)(hsb + b) = v;
        }
        return;
    }
    id -= 1024;   // gate: 1024 blocks x 4 tokens
    int lane = threadIdx.x & 63;
    int t = id * 4 + (threadIdx.x >> 6);
    float acc[NE];
#pragma unroll
    for (int e = 0; e < NE; ++e) acc[e] = 0.f;
    const float* x = hs + (size_t)t * H_DIM;
    for (int i = lane; i < H_DIM; i += 64) {
        float xv = x[i];
#pragma unroll
        for (int e = 0; e < NE; ++e) acc[e] += xv * gw[e * H_DIM + i];
    }
#pragma unroll
    for (int e = 0; e < NE; ++e)
        for (int off = 32; off > 0; off >>= 1) acc[e] += __shfl_xor(acc[e], off);
    if (lane == 0) {
        int i1 = 0; float l1 = acc[0];
#pragma unroll
        for (int e = 1; e < NE; ++e) if (acc[e] > l1) { l1 = acc[e]; i1 = e; }
        int i2 = -1; float l2 = -1e30f;
#pragma unroll
        for (int e = 0; e < NE; ++e) if (e != i1 && acc[e] > l2) { l2 = acc[e]; i2 = e; }
        float aa = __expf(l2 - l1);
        float s = 1.f / (1.f + aa);
        re[t * 2] = i1; re[t * 2 + 1] = i2;
        rw[t * 2] = s;  rw[t * 2 + 1] = aa * s;
        atomicAdd(&counts[i1], 1);
        atomicAdd(&counts[i2], 1);
    }
}

__global__ void scan_kernel(int* __restrict__ meta) {
    if (threadIdx.x == 0) {
        int s = 0;
        for (int e = 0; e < NE; ++e) { meta[8 + e] = s; meta[16 + e] = s; s += meta[e]; }
    }
}

__global__ void place_kernel(const int* __restrict__ re, const float* __restrict__ rw,
                             int* __restrict__ cursor, int* __restrict__ btok,
                             float* __restrict__ bwv, int* __restrict__ tpos) {
    int t = blockIdx.x * 256 + threadIdx.x;
    if (t >= T_TOK) return;
#pragma unroll
    for (int s = 0; s < 2; ++s) {
        int e = re[t * 2 + s];
        int p = atomicAdd(&cursor[e], 1);
        btok[p] = t;
        bwv[p] = rw[t * 2 + s];
        tpos[t * 2 + s] = p;
    }
}

// Panel-pinned XCD decode (validated R3-R14): panel P = sg*8 + (id&7) lives entirely
// on XCD id%8 (its 32 by-blocks are ids sg*256 + by*8 + x, all congruent mod 8).
__device__ __forceinline__ void decode_panel(int id, int npx, int e_arg,
                                             int& e, int& bx, int& by) {
    if (e_arg >= 0) { e = e_arg; bx = id >> 5; by = id & 31; return; }
    int sg  = id >> 8;
    int rem = id & 255;
    by = rem >> 3;
    int P = sg * 8 + (rem & 7);
    e = P / npx; bx = P % npx;
}

// ---------------- GEMM1 (+fused w2 convert): h = silu(X@Wg^T) * (X@Wu^T) ----------------
// m97-style single-buffer 2-barrier loop, all operands via global_load_lds (f16).
// LDS 32 KB -> 4 blocks/CU. BM=128 tokens x (64 g + 64 u cols), BK=64, 256 thr / 4
// waves (2m x 2n), wave = 64 rows x (32 g + 32 u). (validated R11/R12: 513us full)
// Blocks with id < cvt_blocks stream-convert w2 -> w2f (rides in gemm1's HBM headroom).
__global__ __launch_bounds__(256, 4) void gemm1_kernel(
    const f16* __restrict__ w13f, const f16* __restrict__ hsb, f16* __restrict__ hb,
    const int* __restrict__ counts, const int* __restrict__ offs,
    const int* __restrict__ btok,
    const float* __restrict__ w2src, f16* __restrict__ w2dst, int cvt_n8, int cvt_blocks,
    int e_arg, int global_h)
{
    if ((int)blockIdx.x < cvt_blocks) {
        int stride = cvt_blocks * 256;
        for (int i = blockIdx.x * 256 + threadIdx.x; i < cvt_n8; i += stride) {
            size_t b = (size_t)i * 8;
            float4 a = *(const float4*)(w2src + b);
            float4 c = *(const float4*)(w2src + b + 4);
            f16x8 v;
            v[0] = (f16)a.x; v[1] = (f16)a.y; v[2] = (f16)a.z; v[3] = (f16)a.w;
            v[4] = (f16)c.x; v[5] = (f16)c.y; v[6] = (f16)c.z; v[7] = (f16)c.w;
            *(f16x8*)(w2dst + b) = v;
        }
        return;
    }
    int e, bx, by;
    decode_panel((int)blockIdx.x - cvt_blocks, 88, e_arg, e, bx, by);
    const int n_e = counts[e];
    if (by * 128 >= n_e) return;
    const int boff = offs[e];
    const f16* We = (e_arg >= 0) ? w13f : (w13f + (size_t)e * (2 * I_DIM) * H_DIM);

    const int tid = threadIdx.x;
    const int lane = tid & 63;
    const int wid = tid >> 6;
    const int wm = wid >> 1, wn = wid & 1;
    const int l15 = lane & 15;

    __shared__ f16 As[128 * 64];   // 16 KB
    __shared__ f16 Bs[128 * 64];   // 16 KB (rows 0-63 g, 64-127 u)

    const f16* gA[4]; const f16* gB[4]; int dstc[4];
#pragma unroll
    for (int i = 0; i < 4; ++i) {
        int c = i * 256 + tid;
        int r = c >> 3;
        dstc[i] = c * 16;
        int slot = ((c & 7) ^ (r & 7)) * 8;
        int idx = by * 128 + r;
        idx = idx < n_e ? idx : n_e - 1;
        gA[i] = hsb + (size_t)btok[boff + idx] * H_DIM + slot;
        int wrow = (r < 64) ? (bx * 64 + r) : (I_DIM + bx * 64 + (r - 64));
        gB[i] = We + (size_t)wrow * H_DIM + slot;
    }

    f32x4 ag[4][2], au[4][2];
#pragma unroll
    for (int m = 0; m < 4; ++m)
#pragma unroll
        for (int n = 0; n < 2; ++n) { ag[m][n] = (f32x4)0.f; au[m][n] = (f32x4)0.f; }

    const int NT = H_DIM / 64;   // 32

#pragma unroll 1
    for (int kt = 0; kt < NT; ++kt) {
        __syncthreads();
        const int k0 = kt * 64;
#pragma unroll
        for (int i = 0; i < 4; ++i) {
            __builtin_amdgcn_global_load_lds((guint*)(gA[i] + k0), (luint*)((char*)As + dstc[i]), 16, 0, 0);
            __builtin_amdgcn_global_load_lds((guint*)(gB[i] + k0), (luint*)((char*)Bs + dstc[i]), 16, 0, 0);
        }
        __syncthreads();          // implicit vmcnt(0): tile kt landed
#pragma unroll
        for (int kh = 0; kh < 2; ++kh) {
            const int kb = kh * 64 + (lane >> 4) * 16;
            f16x8 a[4], bg[2], bu[2];
#pragma unroll
            for (int m = 0; m < 4; ++m) {
                int r = wm * 64 + m * 16 + l15;
                a[m] = *(const f16x8*)((const char*)As + r * 128 + swzk(r, kb));
            }
#pragma unroll
            for (int n = 0; n < 2; ++n) {
                int rg = wn * 32 + n * 16 + l15;
                bg[n] = *(const f16x8*)((const char*)Bs + rg * 128 + swzk(rg, kb));
                int ru = 64 + rg;
                bu[n] = *(const f16x8*)((const char*)Bs + ru * 128 + swzk(ru, kb));
            }
#pragma unroll
            for (int m = 0; m < 4; ++m)
#pragma unroll
                for (int n = 0; n < 2; ++n) {
                    ag[m][n] = __builtin_amdgcn_mfma_f32_16x16x32_f16(a[m], bg[n], ag[m][n], 0, 0, 0);
                    au[m][n] = __builtin_amdgcn_mfma_f32_16x16x32_f16(a[m], bu[n], au[m][n], 0, 0, 0);
                }
        }
    }

    // epilogue: silu(g)*u -> f16 h
    const int hbase = (global_h ? boff : 0) + by * 128;
#pragma unroll
    for (int m = 0; m < 4; ++m) {
        int rl0 = wm * 64 + m * 16 + ((lane >> 4) << 2);
#pragma unroll
        for (int r = 0; r < 4; ++r) {
            int rl = rl0 + r;
            if (by * 128 + rl < n_e) {
#pragma unroll
                for (int n = 0; n < 2; ++n) {
                    float g = ag[m][n][r];
                    float u = au[m][n][r];
                    float h = g / (1.f + __expf(-g)) * u;
                    hb[(size_t)(hbase + rl) * I_DIM + bx * 64 + wn * 32 + n * 16 + l15] = (f16)h;
                }
            }
        }
    }
}

// ---------------- GEMM2: y[p] = h[p] @ w2^T  (atomic-free, f16 y) ----------------
// R12-exact single-buffer 2-barrier loop: BM=128 x BN=128, BK=64, 4 waves, wave 64x64.
__global__ __launch_bounds__(256, 4) void gemm2_kernel(
    const f16* __restrict__ w2f, const f16* __restrict__ hb, f16* __restrict__ y,
    const int* __restrict__ counts, const int* __restrict__ offs,
    const int* __restrict__ btok, int e_arg, int global_h)
{
    int e, bx, by;
    decode_panel(blockIdx.x, 16, e_arg, e, bx, by);
    const int n_e = counts[e];
    if (by * 128 >= n_e) return;
    const int boff = offs[e];
    const f16* We = (e_arg >= 0) ? w2f : (w2f + (size_t)e * H_DIM * I_DIM);

    const int tid = threadIdx.x;
    const int lane = tid & 63;
    const int wid = tid >> 6;
    const int wm = wid >> 1, wn = wid & 1;
    const int l15 = lane & 15;

    __shared__ f16 As[128 * 64];
    __shared__ f16 Bs[128 * 64];

    const int hb0 = global_h ? boff : 0;
    const f16* gA[4]; const f16* gB[4]; int dstc[4];
#pragma unroll
    for (int i = 0; i < 4; ++i) {
        int c = i * 256 + tid;
        int r = c >> 3;
        dstc[i] = c * 16;
        int slot = ((c & 7) ^ (r & 7)) * 8;
        int idx = by * 128 + r;
        idx = idx < n_e ? idx : n_e - 1;
        gA[i] = hb + (size_t)(hb0 + idx) * I_DIM + slot;
        gB[i] = We + (size_t)(bx * 128 + r) * I_DIM + slot;
    }

    f32x4 acc[4][4];
#pragma unroll
    for (int m = 0; m < 4; ++m)
#pragma unroll
        for (int n = 0; n < 4; ++n) acc[m][n] = (f32x4)0.f;

    const int NT = I_DIM / 64;   // 88

#pragma unroll 1
    for (int kt = 0; kt < NT; ++kt) {
        __syncthreads();
        const int k0 = kt * 64;
#pragma unroll
        for (int i = 0; i < 4; ++i) {
            __builtin_amdgcn_global_load_lds((guint*)(gA[i] + k0), (luint*)((char*)As + dstc[i]), 16, 0, 0);
            __builtin_amdgcn_global_load_lds((guint*)(gB[i] + k0), (luint*)((char*)Bs + dstc[i]), 16, 0, 0);
        }
        __syncthreads();
#pragma unroll
        for (int kh = 0; kh < 2; ++kh) {
            const int kb = kh * 64 + (lane >> 4) * 16;
            f16x8 a[4], b[4];
#pragma unroll
            for (int m = 0; m < 4; ++m) {
                int r = wm * 64 + m * 16 + l15;
                a[m] = *(const f16x8*)((const char*)As + r * 128 + swzk(r, kb));
            }
#pragma unroll
            for (int n = 0; n < 4; ++n) {
                int r = wn * 64 + n * 16 + l15;
                b[n] = *(const f16x8*)((const char*)Bs + r * 128 + swzk(r, kb));
            }
#pragma unroll
            for (int m = 0; m < 4; ++m)
#pragma unroll
                for (int n = 0; n < 4; ++n)
                    acc[m][n] = __builtin_amdgcn_mfma_f32_16x16x32_f16(a[m], b[n], acc[m][n], 0, 0, 0);
        }
    }

    // epilogue: plain f16 stores into y (each bucket row owned by exactly one block)
#pragma unroll
    for (int m = 0; m < 4; ++m) {
        int rl0 = wm * 64 + m * 16 + ((lane >> 4) << 2);
#pragma unroll
        for (int r = 0; r < 4; ++r) {
            int rl = rl0 + r;
            if (by * 128 + rl < n_e) {
                int p = boff + by * 128 + rl;
#pragma unroll
                for (int n = 0; n < 4; ++n)
                    y[(size_t)p * H_DIM + bx * 128 + wn * 64 + n * 16 + l15] = (f16)acc[m][n][r];
            }
        }
    }
}

// ---------------- reduce: out[t] = w0*y[p0] + w1*y[p1]  (f16 y) ----------------
__global__ void reduce_kernel(const f16* __restrict__ y, const int* __restrict__ tpos,
                              const float* __restrict__ bwv, float* __restrict__ out) {
    int t = blockIdx.x;
    int p0 = tpos[t * 2], p1 = tpos[t * 2 + 1];
    float w0 = bwv[p0], w1 = bwv[p1];
    const f16x8* y0 = (const f16x8*)(y + (size_t)p0 * H_DIM);
    const f16x8* y1 = (const f16x8*)(y + (size_t)p1 * H_DIM);
    float4* o = (float4*)(out + (size_t)t * H_DIM);
    for (int i = threadIdx.x; i < H_DIM / 8; i += 256) {
        f16x8 a = y0[i], b = y1[i];
        float4 r0, r1;
        r0.x = w0 * (float)a[0] + w1 * (float)b[0];
        r0.y = w0 * (float)a[1] + w1 * (float)b[1];
        r0.z = w0 * (float)a[2] + w1 * (float)b[2];
        r0.w = w0 * (float)a[3] + w1 * (float)b[3];
        r1.x = w0 * (float)a[4] + w1 * (float)b[4];
        r1.y = w0 * (float)a[5] + w1 * (float)b[5];
        r1.z = w0 * (float)a[6] + w1 * (float)b[6];
        r1.w = w0 * (float)a[7] + w1 * (float)b[7];
        o[i * 2]     = r0;
        o[i * 2 + 1] = r1;
    }
}

extern "C" void kernel_launch(void* const* d_in, const int* in_sizes, int n_in,
                              void* d_out, int out_size, void* d_ws, size_t ws_size,
                              hipStream_t stream) {
    const float* hs  = (const float*)d_in[0];
    const float* gw  = (const float*)d_in[1];
    const float* w13 = (const float*)d_in[2];
    const float* w2  = (const float*)d_in[3];
    float* out = (float*)d_out;

    char* ws = (char*)d_ws;
    int*   meta = (int*)(ws + OFF_META);
    int*   btok = (int*)(ws + OFF_BTOK);
    float* bwv  = (float*)(ws + OFF_BW);
    int*   re   = (int*)(ws + OFF_RE);
    float* rw   = (float*)(ws + OFF_RW);
    int*   tpos = (int*)(ws + OFF_TP);
    f16*   hsb  = (f16*)(ws + OFF_HSB);

    hipMemsetAsync(meta, 0, 256, stream);

    const size_t w13_elems = (size_t)NE * 2 * I_DIM * H_DIM;   // 184,549,376
    const size_t w2_elems  = (size_t)NE * H_DIM * I_DIM;       //  92,274,688

    // full-f16 path layout
    size_t o_w13f = OFF_WF;
    size_t o_w2f  = o_w13f + w13_elems * 2;
    size_t o_hb   = o_w2f + w2_elems * 2;
    size_t o_y    = o_hb + (size_t)2 * T_TOK * I_DIM * 2;
    size_t need_full = o_y + (size_t)2 * T_TOK * H_DIM * 2;

    // per-expert fallback layout
    size_t f_w13 = OFF_WF;
    size_t f_w2  = f_w13 + (size_t)2 * I_DIM * H_DIM * 2;
    size_t f_hb  = f_w2 + (size_t)H_DIM * I_DIM * 2;
    size_t f_y   = f_hb + (size_t)T_TOK * I_DIM * 2;

    if (ws_size >= need_full) {
        f16* w13f = (f16*)(ws + o_w13f);
        f16* w2f  = (f16*)(ws + o_w2f);
        f16* hb   = (f16*)(ws + o_hb);
        f16* y    = (f16*)(ws + o_y);
        // fused prep: 3072 w13-cvt + 1024 hs-cvt + 1024 gate blocks
        prep_kernel<<<3072 + 1024 + 1024, 256, 0, stream>>>(
            w13, w13f, (int)(w13_elems / 8), 3072, hs, hsb, gw, re, rw, meta);
        scan_kernel<<<1, 64, 0, stream>>>(meta);
        place_kernel<<<T_TOK / 256, 256, 0, stream>>>(re, rw, meta + 16, btok, bwv, tpos);
        // gemm1: 2048 fused w2-convert blocks + 704 panels x 32 by
        gemm1_kernel<<<2048 + 704 * 32, 256, 0, stream>>>(
            w13f, hsb, hb, meta, meta + 8, btok,
            w2, w2f, (int)(w2_elems / 8), 2048, -1, 1);
        gemm2_kernel<<<128 * 32, 256, 0, stream>>>(w2f, hb, y, meta, meta + 8, btok, -1, 1);
        reduce_kernel<<<T_TOK, 256, 0, stream>>>(y, tpos, bwv, out);
    } else {
        f16* w13f = (f16*)(ws + f_w13);
        f16* w2f  = (f16*)(ws + f_w2);
        f16* hb   = (f16*)(ws + f_hb);
        f16* y    = (f16*)(ws + f_y);
        prep_kernel<<<1024 + 1024, 256, 0, stream>>>(
            w13, (f16*)nullptr, 0, 0, hs, hsb, gw, re, rw, meta);
        scan_kernel<<<1, 64, 0, stream>>>(meta);
        place_kernel<<<T_TOK / 256, 256, 0, stream>>>(re, rw, meta + 16, btok, bwv, tpos);
        const size_t w13_slice = (size_t)2 * I_DIM * H_DIM;
        const size_t w2_slice  = (size_t)H_DIM * I_DIM;
        for (int e = 0; e < NE; ++e) {
            cvt_w_kernel<<<2048, 256, 0, stream>>>(w13 + e * w13_slice, w13f, (int)(w13_slice / 8));
            gemm1_kernel<<<2048 + 88 * 32, 256, 0, stream>>>(
                w13f, hsb, hb, meta, meta + 8, btok,
                w2 + e * w2_slice, w2f, (int)(w2_slice / 8), 2048, e, 0);
            gemm2_kernel<<<16 * 32, 256, 0, stream>>>(w2f, hb, y, meta, meta + 8, btok, e, 0);
        }
        reduce_kernel<<<T_TOK, 256, 0, stream>>>(y, tpos, bwv, out);
    }
}